// Round 5
// baseline (3129.078 us; speedup 1.0000x reference)
//
#include <hip/hip_runtime.h>
#include <stdint.h>
#include <stddef.h>

// ---------------------------------------------------------------------------
// LSTM (B=64, T=1024, I=256, H=512) + attention pooling on MI355X (gfx950).
//   k_lstm v9: 64 blocks x 1024 thr (16 waves); 8 chains x 8 blocks
//   (8 batches x 64 units per block). Sentinel protocol from v8 unchanged:
//   hs slabs 1..1024 pre-poisoned 0xFEFE; h finite => stored f16 never equals
//   sentinel; consumers gather h(t-1) directly (device scope sc0 sc1) and
//   retry stale lanes -- poll and gather are the same load; producers store
//   with no drain/flag.
//   KEY CHANGES vs v8 (coherent-request-rate attack, per v4's measurement
//   that the LLC services ~22 coherent req/us):
//   1) chains 16->8 blocks: each h row re-fetched by 8 consumers not 16 ->
//      gather traffic 1MB -> 512KB/step; lockstep tail halved; per-wave MFMA
//      structure identical (wave owns 4 units).
//   2) xT staged via LDS (waves 8..11, plain cached loads, double-buffered):
//      x-projection MFMA reads LDS -> no VMEM waits on the serial path and
//      no 16-wave duplication of xT reads.
// ---------------------------------------------------------------------------

typedef _Float16 f16_t;
typedef _Float16 half8 __attribute__((ext_vector_type(8)));
typedef float f32x4 __attribute__((ext_vector_type(4)));

#define MFMA16(a, b, c) __builtin_amdgcn_mfma_f32_16x16x32_f16((a), (b), (c), 0, 0, 0)

static constexpr int BATCH = 64;
static constexpr int TLEN = 1024;
static constexpr int IDIM = 256;
static constexpr int HDIM = 512;

__device__ __forceinline__ float sigf(float x) { return 1.f / (1.f + __expf(-x)); }
__device__ __forceinline__ float tanh_fast(float x) {
  float e = __expf(2.f * fabsf(x));
  float t = 1.f - 2.f / (e + 1.f);
  return copysignf(t, x);
}
__device__ __forceinline__ half8 load_cvt8(const float* p) {
  f32x4 a = *(const f32x4*)p;
  f32x4 b = *(const f32x4*)(p + 4);
  half8 r;
#pragma unroll
  for (int j = 0; j < 4; ++j) { r[j] = (f16_t)a[j]; r[4 + j] = (f16_t)b[j]; }
  return r;
}

// device-scope (sc0 sc1) 16B load with completion wait: IC is the coherence
// point across XCDs -- the path v4/v6/v8 validated.
__device__ __forceinline__ f32x4 ld16_llc(const f16_t* p) {
  f32x4 v;
  asm volatile("global_load_dwordx4 %0, %1, off sc0 sc1\n\ts_waitcnt vmcnt(0)"
               : "=&v"(v) : "v"(p) : "memory");
  return v;
}

// true iff none of the 8 f16 lanes equals the 0xFEFE sentinel
__device__ __forceinline__ bool clean16(const f32x4& v) {
  const unsigned* u = (const unsigned*)&v;
  bool ok = true;
#pragma unroll
  for (int i = 0; i < 4; ++i) {
    ok = ok && ((u[i] & 0xFFFFu) != 0xFEFEu);
    ok = ok && ((u[i] >> 16) != 0xFEFEu);
  }
  return ok;
}

// ---------------------------------------------------------------------------
__global__ __launch_bounds__(256) void k_prep_x(const float* __restrict__ x,
                                                f16_t* __restrict__ xT) {
  __shared__ f16_t sx[64][IDIM + 8];
  const int t = blockIdx.x;
  const int tid = threadIdx.x;
#pragma unroll 4
  for (int b = 0; b < 64; ++b)
    sx[b][tid] = (f16_t)x[((size_t)b * TLEN + t) * IDIM + tid];
  __syncthreads();
#pragma unroll
  for (int it = 0; it < 8; ++it) {
    const int c = it * 256 + tid;      // c = kk4*64 + b
    const int b = c & 63, kk4 = c >> 6;
    half8 v = *(const half8*)&sx[b][kk4 * 8];
    *(half8*)(xT + (((size_t)t * 32 + kk4) * 64 + b) * 8) = v;
  }
}

__global__ __launch_bounds__(256) void k_prep_w(const float* __restrict__ Wa,
                                                f16_t* __restrict__ WaT) {
  const int id = blockIdx.x * 256 + threadIdx.x;   // 0..32767
  const int n = id & 511, kk4 = id >> 9;
  half8 v = load_cvt8(&Wa[(size_t)n * HDIM + kk4 * 8]);
  *(half8*)(WaT + ((size_t)kk4 * HDIM + n) * 8) = v;
}

// ---------------------------------------------------------------------------
// Recurrence. Roles static: bg = bid&7 (chain), ug = bid>>3 (0..7).
// Batches bg*8..+7, units ug*64..+63. Wave w (0..15): units u0=ug*64+w*4..+3.
// MFMA M rows [unit][gate]; N lanes col 0..15 carry batch (col&7) (cols
// 8..15 duplicate, discarded on store). Phase 1: waves 0..7 gather h(t-1)
// rows (sentinel retry); waves 8..11 stage xT slice t+1 -> LDS (cached).
// ---------------------------------------------------------------------------
__global__ __launch_bounds__(1024) void k_lstm(
    const float* __restrict__ Whh, const float* __restrict__ Wih,
    const float* __restrict__ bih, const float* __restrict__ bhh,
    const f16_t* __restrict__ xT, f16_t* __restrict__ hs) {
  const int tid = threadIdx.x;
  const int w = tid >> 6;                  // wave 0..15
  const int L = tid & 63;
  const int q = L >> 4, col = L & 15;
  const int bid = blockIdx.x;              // 0..63
  const int bg = bid & 7;                  // chain / batch group
  const int ug = bid >> 3;                 // 0..7 unit group

  const int u0 = ug * 64 + w * 4;
  const int b8 = col & 7;                  // chain-local batch
  const int bglob = bg * 8 + b8;           // global batch
  const int myu = u0 + q;

  __shared__ __align__(16) f16_t hin[8][520];      // h(t-1): 1040B stride
  __shared__ __align__(16) f16_t hout[8][72];      // block's h(t): 144B stride
  __shared__ __align__(16) f16_t xbuf[2][32][72];  // xT slice dbuf: 144B rows

  // Persistent A-fragments: A[m=col][k=q*8+j]; m = unit_local*4 + gate.
  const int arow = (col & 3) * HDIM + u0 + (col >> 2);
  half8 wAh[16], wAx[8];
#pragma unroll
  for (int kk = 0; kk < 16; ++kk)
    wAh[kk] = load_cvt8(&Whh[(size_t)arow * HDIM + kk * 32 + q * 8]);
#pragma unroll
  for (int kk = 0; kk < 8; ++kk)
    wAx[kk] = load_cvt8(&Wih[(size_t)arow * IDIM + kk * 32 + q * 8]);

  float pb[4];
#pragma unroll
  for (int r = 0; r < 4; ++r) pb[r] = bih[r * HDIM + myu] + bhh[r * HDIM + myu];

  // prologue-only: x-projection from global
  auto xgemm_g = [&](int t) {
    f32x4 a = {0.f, 0.f, 0.f, 0.f};
#pragma unroll
    for (int kk = 0; kk < 8; ++kk) {
      half8 bf = *(const half8*)(xT +
          (((size_t)(t - 1) * 32 + kk * 4 + q) * 64 + bglob) * 8);
      a = MFMA16(wAx[kk], bf, a);
    }
    return a;
  };
  // steady-state: x-projection from LDS-staged slice
  auto xgemm_l = [&](int par) {
    f32x4 a = {0.f, 0.f, 0.f, 0.f};
#pragma unroll
    for (int kk = 0; kk < 8; ++kk) {
      half8 bf = *(const half8*)&xbuf[par][kk * 4 + q][b8 * 8];
      a = MFMA16(wAx[kk], bf, a);
    }
    return a;
  };

  float c = 0.f;
  f32x4 xacc = xgemm_g(1);
  for (int t = 1; t <= TLEN; ++t) {
    // ---- phase 1: gather h(t-1) (waves 0..7) / stage xT t+1 (waves 8..11) -
    if (w < 8) {
      const f16_t* src = hs + ((size_t)(t - 1) * BATCH + bg * 8 + w) * HDIM
                         + L * 8;          // 16B per lane, 1KB per wave
      f32x4 v = ld16_llc(src);
      int guard = 0;
      for (;;) {
        const bool ok = clean16(v);
        if (__ballot(ok) == ~0ull) break;
        if (!ok) v = ld16_llc(src);        // exec-masked retry
        if (++guard > (1 << 22)) break;    // fail loud, not hung
      }
      *(f32x4*)&hin[w][L * 8] = v;
    } else if (w < 12 && t < TLEN) {
      const int idx = (w - 8) * 64 + L;    // 0..255
      const int kk4 = idx >> 3, bb = idx & 7;
      const f16_t* src = xT + (((size_t)t * 32 + kk4) * 64 + bg * 8 + bb) * 8;
      *(f32x4*)&xbuf[(t + 1) & 1][kk4][bb * 8] = *(const f32x4*)src;
    }
    __syncthreads();                       // hin + xbuf complete

    // ---- MFMA: B-frags broadcast-read from LDS, dual accumulators ----
    f32x4 a0 = xacc, a1 = {0.f, 0.f, 0.f, 0.f};
#pragma unroll
    for (int kk = 0; kk < 16; kk += 2) {
      half8 b0 = *(const half8*)&hin[b8][kk * 32 + q * 8];
      half8 b1 = *(const half8*)&hin[b8][(kk + 1) * 32 + q * 8];
      a0 = MFMA16(wAh[kk], b0, a0);
      a1 = MFMA16(wAh[kk + 1], b1, a1);
    }
    const f32x4 acc = a0 + a1;

    const float ig = sigf(acc[0] + pb[0]);
    const float fg = sigf(acc[1] + pb[1]);
    const float gg = tanh_fast(acc[2] + pb[2]);
    const float og = sigf(acc[3] + pb[3]);
    c = fg * c + ig * gg;
    if (col < 8) hout[col][w * 4 + q] = (f16_t)(og * tanh_fast(c));

    __syncthreads();                       // hout ready, hin consumed

    // ---- wave 0: 8 batches x 128B coalesced stores; no drain, no flag ----
    if (w == 0) {
      const int sb = L >> 3, ck = L & 7;   // batch, 16B chunk
      f32x4 v = *(const f32x4*)&hout[sb][ck * 8];
      f16_t* dst = hs + ((size_t)t * BATCH + bg * 8 + sb) * HDIM
                   + ug * 64 + ck * 8;
      asm volatile("global_store_dwordx4 %0, %1, off sc0 sc1"
                   :: "v"(dst), "v"(v) : "memory");
    }

    // x-projection for the NEXT step from LDS: no VMEM on the serial path
    if (t < TLEN) xacc = xgemm_l((t + 1) & 1);
  }
}

// ---------------------------------------------------------------------------
__global__ __launch_bounds__(256) void k_attn(
    const f16_t* __restrict__ hse, const f16_t* __restrict__ WaT,
    const float* __restrict__ battn, f16_t* __restrict__ E) {
  const int w = threadIdx.x >> 6;
  const int L = threadIdx.x & 63;
  const int q = L >> 4, col = L & 15;
  const int m0 = blockIdx.x * 64 + w * 16;   // r rows (r = t*64+b)
  const int n0 = blockIdx.y * 64;            // h cols

  f32x4 acc[4];
#pragma unroll
  for (int nt = 0; nt < 4; ++nt) acc[nt] = {0.f, 0.f, 0.f, 0.f};

#pragma unroll 4
  for (int kk = 0; kk < 16; ++kk) {          // K = 512
    half8 af = *(const half8*)(hse + (size_t)(m0 + col) * HDIM + kk * 32 + q * 8);
#pragma unroll
    for (int nt = 0; nt < 4; ++nt) {
      half8 bf = *(const half8*)(WaT +
          ((size_t)(kk * 4 + q) * HDIM + n0 + nt * 16 + col) * 8);
      acc[nt] = MFMA16(af, bf, acc[nt]);
    }
  }
#pragma unroll
  for (int nt = 0; nt < 4; ++nt) {
    const int h = n0 + nt * 16 + col;
    const float bias = battn[h];
#pragma unroll
    for (int r = 0; r < 4; ++r) {
      const int m = m0 + q * 4 + r;
      E[(size_t)m * HDIM + h] = (f16_t)__expf(tanh_fast(acc[nt][r] + bias));
    }
  }
}

__global__ __launch_bounds__(256) void k_pool(
    const f16_t* __restrict__ E, const f16_t* __restrict__ hse,
    float* __restrict__ pnum, float* __restrict__ pden) {
  const int b = blockIdx.x;
  const int hc = blockIdx.y;
  const int tc = blockIdx.z;
  const int h = hc * 256 + threadIdx.x;
  float num = 0.f, den = 0.f;
#pragma unroll 4
  for (int tt = 0; tt < 256; ++tt) {
    const int t = tc * 256 + tt;
    const size_t idx = ((size_t)t * BATCH + b) * HDIM + h;
    const float e = (float)E[idx];
    const float hv = (float)hse[idx];
    den += e;
    num += e * hv;
  }
  const size_t pi = ((size_t)tc * BATCH + b) * HDIM + h;
  pnum[pi] = num;
  pden[pi] = den;
}

__global__ __launch_bounds__(256) void k_final(
    const float* __restrict__ pnum, const float* __restrict__ pden,
    float* __restrict__ out) {
  const int i = blockIdx.x * 256 + threadIdx.x;   // b*512+h
  float n = 0.f, d = 0.f;
#pragma unroll
  for (int z = 0; z < 4; ++z) {
    n += pnum[(size_t)z * 32768 + i];
    d += pden[(size_t)z * 32768 + i];
  }
  out[i] = n / d;
}

// ---------------------------------------------------------------------------
extern "C" void kernel_launch(void* const* d_in, const int* in_sizes, int n_in,
                              void* d_out, int out_size, void* d_ws, size_t ws_size,
                              hipStream_t stream) {
  const float* x   = (const float*)d_in[0];
  const float* Wih = (const float*)d_in[1];
  const float* Whh = (const float*)d_in[2];
  const float* bih = (const float*)d_in[3];
  const float* bhh = (const float*)d_in[4];
  const float* Wat = (const float*)d_in[5];
  const float* bat = (const float*)d_in[6];
  float* out = (float*)d_out;

  char* ws = (char*)d_ws;
  const size_t REGA_BYTES = (size_t)64 * 1024 * 1024;                        // xT then E
  const size_t HS_BYTES = (size_t)(TLEN + 1) * BATCH * HDIM * sizeof(f16_t); // 67.2MB
  const size_t WAT_BYTES = (size_t)64 * HDIM * 8 * sizeof(f16_t);            // 512KB
  const size_t P_BYTES = (size_t)4 * BATCH * HDIM * sizeof(float);           // 512KB

  f16_t* xT = (f16_t*)ws;
  f16_t* E  = (f16_t*)ws;
  f16_t* hs = (f16_t*)(ws + REGA_BYTES);
  f16_t* WaT = (f16_t*)(ws + REGA_BYTES + HS_BYTES);
  float* pnum = (float*)(ws + REGA_BYTES + HS_BYTES + WAT_BYTES);
  float* pden = (float*)(ws + REGA_BYTES + HS_BYTES + WAT_BYTES + P_BYTES);

  const size_t SLAB = (size_t)BATCH * HDIM * sizeof(f16_t);   // 64KB
  // slab 0 = h(0) = zeros; slabs 1..1024 = 0xFEFE sentinel (re-poison every
  // launch: the sentinel IS the readiness protocol).
  hipMemsetAsync(hs, 0, SLAB, stream);
  hipMemsetAsync((char*)hs + SLAB, 0xFE, (size_t)TLEN * SLAB, stream);

  k_prep_x<<<dim3(TLEN), 256, 0, stream>>>(x, xT);
  k_prep_w<<<dim3(128), 256, 0, stream>>>(Wat, WaT);
  k_lstm<<<dim3(64), 1024, 0, stream>>>(Whh, Wih, bih, bhh, xT, hs);

  const f16_t* hse = hs + (size_t)BATCH * HDIM;   // slab 1 == reference hs[0]
  k_attn<<<dim3(1024, 8), 256, 0, stream>>>(hse, WaT, bat, E);
  k_pool<<<dim3(64, 2, 4), 256, 0, stream>>>(E, hse, pnum, pden);
  k_final<<<dim3(128), 256, 0, stream>>>(pnum, pden, out);
}

// Round 6
// 3049.851 us; speedup vs baseline: 1.0260x; 1.0260x over previous
//
#include <hip/hip_runtime.h>
#include <stdint.h>
#include <stddef.h>

// ---------------------------------------------------------------------------
// LSTM (B=64, T=1024, I=256, H=512) + attention pooling on MI355X (gfx950).
//   k_lstm v10: v8 skeleton VERBATIM (128 blocks x 512 thr; 8 chains x 16
//   blocks of 8 batches x 32 units; sentinel-carrying h at device scope;
//   ~100 VGPR, launch_bounds(512,2)). v9 post-mortem: launch_bounds(1024)
//   capped VGPRs at 64 < the 96 needed for persistent weights -> spills ->
//   regression. Reverted wholesale.
//   KEY CHANGES vs v8 (attack the poll loop, not the legs):
//   1) issue-early prefetch: the gather load for step t+1 is ISSUED (no
//      wait) right after the h(t) store; its ~900cy flight overlaps
//      xgemm(t+1); the loop top only waits (vmcnt(0) tied to the value).
//   2) alternating-scope retry with per-lane latch: retries alternate
//      sc0 sc1 (authoritative IC probe, guarantees progress) with sc0-only
//      (XCD-L2 probe, ~200cy). hs lines are write-once per run and launch-
//      acquire invalidates L2s (standard inter-kernel semantics), so any
//      non-sentinel value at any scope is the true h. Same-XCD consumers
//      detect via cheap L2 hits; remote consumers' IC poll pressure ~halves.
// ---------------------------------------------------------------------------

typedef _Float16 f16_t;
typedef _Float16 half8 __attribute__((ext_vector_type(8)));
typedef float f32x4 __attribute__((ext_vector_type(4)));

#define MFMA16(a, b, c) __builtin_amdgcn_mfma_f32_16x16x32_f16((a), (b), (c), 0, 0, 0)

static constexpr int BATCH = 64;
static constexpr int TLEN = 1024;
static constexpr int IDIM = 256;
static constexpr int HDIM = 512;

__device__ __forceinline__ float sigf(float x) { return 1.f / (1.f + __expf(-x)); }
__device__ __forceinline__ float tanh_fast(float x) {
  float e = __expf(2.f * fabsf(x));
  float t = 1.f - 2.f / (e + 1.f);
  return copysignf(t, x);
}
__device__ __forceinline__ half8 load_cvt8(const float* p) {
  f32x4 a = *(const f32x4*)p;
  f32x4 b = *(const f32x4*)(p + 4);
  half8 r;
#pragma unroll
  for (int j = 0; j < 4; ++j) { r[j] = (f16_t)a[j]; r[4 + j] = (f16_t)b[j]; }
  return r;
}

// device-scope (sc0 sc1) 16B load with completion wait (IC coherence point).
__device__ __forceinline__ f32x4 ld16_llc(const f16_t* p) {
  f32x4 v;
  asm volatile("global_load_dwordx4 %0, %1, off sc0 sc1\n\ts_waitcnt vmcnt(0)"
               : "=&v"(v) : "v"(p) : "memory");
  return v;
}
// XCD-scope probe (sc0: L1-bypass, may hit the local L2). Values are
// write-once so a stale hit can only be the sentinel, never wrong data.
__device__ __forceinline__ f32x4 ld16_l2(const f16_t* p) {
  f32x4 v;
  asm volatile("global_load_dwordx4 %0, %1, off sc0\n\ts_waitcnt vmcnt(0)"
               : "=&v"(v) : "v"(p) : "memory");
  return v;
}
// issue a device-scope 16B load WITHOUT waiting (prefetch)
__device__ __forceinline__ void ld16_issue(const f16_t* p, f32x4* dst) {
  asm volatile("global_load_dwordx4 %0, %1, off sc0 sc1"
               : "=&v"(*dst) : "v"(p) : "memory");
}
// complete all outstanding VMEM; data-ordered on the prefetched value
__device__ __forceinline__ void wait_vm0(f32x4* v) {
  asm volatile("s_waitcnt vmcnt(0)" : "+v"(*v) :: "memory");
}

// true iff none of the 8 f16 lanes equals the 0xFEFE sentinel
__device__ __forceinline__ bool clean16(const f32x4& v) {
  const unsigned* u = (const unsigned*)&v;
  bool ok = true;
#pragma unroll
  for (int i = 0; i < 4; ++i) {
    ok = ok && ((u[i] & 0xFFFFu) != 0xFEFEu);
    ok = ok && ((u[i] >> 16) != 0xFEFEu);
  }
  return ok;
}

// ---------------------------------------------------------------------------
__global__ __launch_bounds__(256) void k_prep_x(const float* __restrict__ x,
                                                f16_t* __restrict__ xT) {
  __shared__ f16_t sx[64][IDIM + 8];
  const int t = blockIdx.x;
  const int tid = threadIdx.x;
#pragma unroll 4
  for (int b = 0; b < 64; ++b)
    sx[b][tid] = (f16_t)x[((size_t)b * TLEN + t) * IDIM + tid];
  __syncthreads();
#pragma unroll
  for (int it = 0; it < 8; ++it) {
    const int c = it * 256 + tid;      // c = kk4*64 + b
    const int b = c & 63, kk4 = c >> 6;
    half8 v = *(const half8*)&sx[b][kk4 * 8];
    *(half8*)(xT + (((size_t)t * 32 + kk4) * 64 + b) * 8) = v;
  }
}

__global__ __launch_bounds__(256) void k_prep_w(const float* __restrict__ Wa,
                                                f16_t* __restrict__ WaT) {
  const int id = blockIdx.x * 256 + threadIdx.x;   // 0..32767
  const int n = id & 511, kk4 = id >> 9;
  half8 v = load_cvt8(&Wa[(size_t)n * HDIM + kk4 * 8]);
  *(half8*)(WaT + ((size_t)kk4 * HDIM + n) * 8) = v;
}

// ---------------------------------------------------------------------------
// Recurrence. Roles static: bg = bid&7 (chain), ug = bid>>3 (rank 0..15).
// Batches bg*8..+7, units ug*32..+31. Wave w (0..7): units u0=ug*32+w*4..+3.
// MFMA M rows [unit][gate]; N lanes col 0..15 carry batch (col&7) (cols
// 8..15 duplicate, discarded on store). h(t) stores into sentinel-poisoned
// hs are self-announcing; gather = poll.
// ---------------------------------------------------------------------------
__global__ __launch_bounds__(512, 2) void k_lstm(
    const float* __restrict__ Whh, const float* __restrict__ Wih,
    const float* __restrict__ bih, const float* __restrict__ bhh,
    const f16_t* __restrict__ xT, f16_t* __restrict__ hs) {
  const int tid = threadIdx.x;
  const int w = tid >> 6;                  // wave 0..7
  const int L = tid & 63;
  const int q = L >> 4, col = L & 15;
  const int bid = blockIdx.x;
  const int bg = bid & 7;                  // chain / batch group
  const int ug = bid >> 3;                 // 0..15 unit group

  const int u0 = ug * 32 + w * 4;
  const int b8 = col & 7;                  // chain-local batch
  const int bglob = bg * 8 + b8;           // global batch
  const int myu = u0 + q;

  __shared__ __align__(16) f16_t hin[8][520];   // h(t-1): 1040B stride
  __shared__ __align__(16) f16_t hout[8][40];   // block's h(t) chunk

  // Persistent A-fragments: A[m=col][k=q*8+j]; m = unit_local*4 + gate.
  const int arow = (col & 3) * HDIM + u0 + (col >> 2);
  half8 wAh[16], wAx[8];
#pragma unroll
  for (int kk = 0; kk < 16; ++kk)
    wAh[kk] = load_cvt8(&Whh[(size_t)arow * HDIM + kk * 32 + q * 8]);
#pragma unroll
  for (int kk = 0; kk < 8; ++kk)
    wAx[kk] = load_cvt8(&Wih[(size_t)arow * IDIM + kk * 32 + q * 8]);

  float pb[4];
#pragma unroll
  for (int r = 0; r < 4; ++r) pb[r] = bih[r * HDIM + myu] + bhh[r * HDIM + myu];

  auto xgemm = [&](int t) {
    f32x4 a = {0.f, 0.f, 0.f, 0.f};
#pragma unroll
    for (int kk = 0; kk < 8; ++kk) {
      half8 bf = *(const half8*)(xT +
          (((size_t)(t - 1) * 32 + kk * 4 + q) * 64 + bglob) * 8);
      a = MFMA16(wAx[kk], bf, a);
    }
    return a;
  };

  float c = 0.f;
  f32x4 vg;
  // prefetch gather for t=1: h(0) slab is zeros (never sentinel)
  ld16_issue(hs + ((size_t)(bg * 8 + w)) * HDIM + L * 8, &vg);
  f32x4 xacc = xgemm(1);

  for (int t = 1; t <= TLEN; ++t) {
    // ---- gather h(t-1): wait prefetch, latch clean lanes, alternate-scope
    //      retry (sc0 sc1 authoritative / sc0 local-L2 probe) ----
    {
      const f16_t* src = hs + ((size_t)(t - 1) * BATCH + bg * 8 + w) * HDIM
                         + L * 8;          // 16B per lane, 1KB per wave
      wait_vm0(&vg);
      f32x4 r = vg;
      bool have = clean16(r);
      int it = 0;
      while (__ballot(have) != ~0ull) {
        if (!have) {                       // exec-masked retry, per-lane latch
          f32x4 nv = (it & 1) ? ld16_l2(src) : ld16_llc(src);
          if (clean16(nv)) { r = nv; have = true; }
        }
        if (++it > (1 << 20)) break;       // fail loud, not hung
      }
      *(f32x4*)&hin[w][L * 8] = r;
    }
    __syncthreads();                       // hin complete

    // ---- MFMA: B-frags broadcast-read from LDS, dual accumulators ----
    f32x4 a0 = xacc, a1 = {0.f, 0.f, 0.f, 0.f};
#pragma unroll
    for (int kk = 0; kk < 16; kk += 2) {
      half8 b0 = *(const half8*)&hin[b8][kk * 32 + q * 8];
      half8 b1 = *(const half8*)&hin[b8][(kk + 1) * 32 + q * 8];
      a0 = MFMA16(wAh[kk], b0, a0);
      a1 = MFMA16(wAh[kk + 1], b1, a1);
    }
    const f32x4 acc = a0 + a1;

    const float ig = sigf(acc[0] + pb[0]);
    const float fg = sigf(acc[1] + pb[1]);
    const float gg = tanh_fast(acc[2] + pb[2]);
    const float og = sigf(acc[3] + pb[3]);
    c = fg * c + ig * gg;
    if (col < 8) hout[col][w * 4 + q] = (f16_t)(og * tanh_fast(c));

    __syncthreads();                       // hout ready, hin consumed

    // ---- wave 0: 8x64B coalesced stores; no drain, no flag ----
    if (w == 0 && L < 32) {
      const int sb = L >> 2, q4 = L & 3;
      f32x4 v = *(const f32x4*)&hout[sb][q4 * 8];
      f16_t* dst = hs + ((size_t)t * BATCH + bg * 8 + sb) * HDIM
                   + ug * 32 + q4 * 8;
      asm volatile("global_store_dwordx4 %0, %1, off sc0 sc1"
                   :: "v"(dst), "v"(v) : "memory");
    }

    // issue next gather prefetch NOW (flies during xgemm), then x-projection
    if (t < TLEN) {
      ld16_issue(hs + ((size_t)t * BATCH + bg * 8 + w) * HDIM + L * 8, &vg);
      xacc = xgemm(t + 1);
    }
  }
}

// ---------------------------------------------------------------------------
__global__ __launch_bounds__(256) void k_attn(
    const f16_t* __restrict__ hse, const f16_t* __restrict__ WaT,
    const float* __restrict__ battn, f16_t* __restrict__ E) {
  const int w = threadIdx.x >> 6;
  const int L = threadIdx.x & 63;
  const int q = L >> 4, col = L & 15;
  const int m0 = blockIdx.x * 64 + w * 16;   // r rows (r = t*64+b)
  const int n0 = blockIdx.y * 64;            // h cols

  f32x4 acc[4];
#pragma unroll
  for (int nt = 0; nt < 4; ++nt) acc[nt] = {0.f, 0.f, 0.f, 0.f};

#pragma unroll 4
  for (int kk = 0; kk < 16; ++kk) {          // K = 512
    half8 af = *(const half8*)(hse + (size_t)(m0 + col) * HDIM + kk * 32 + q * 8);
#pragma unroll
    for (int nt = 0; nt < 4; ++nt) {
      half8 bf = *(const half8*)(WaT +
          ((size_t)(kk * 4 + q) * HDIM + n0 + nt * 16 + col) * 8);
      acc[nt] = MFMA16(af, bf, acc[nt]);
    }
  }
#pragma unroll
  for (int nt = 0; nt < 4; ++nt) {
    const int h = n0 + nt * 16 + col;
    const float bias = battn[h];
#pragma unroll
    for (int r = 0; r < 4; ++r) {
      const int m = m0 + q * 4 + r;
      E[(size_t)m * HDIM + h] = (f16_t)__expf(tanh_fast(acc[nt][r] + bias));
    }
  }
}

__global__ __launch_bounds__(256) void k_pool(
    const f16_t* __restrict__ E, const f16_t* __restrict__ hse,
    float* __restrict__ pnum, float* __restrict__ pden) {
  const int b = blockIdx.x;
  const int hc = blockIdx.y;
  const int tc = blockIdx.z;
  const int h = hc * 256 + threadIdx.x;
  float num = 0.f, den = 0.f;
#pragma unroll 4
  for (int tt = 0; tt < 256; ++tt) {
    const int t = tc * 256 + tt;
    const size_t idx = ((size_t)t * BATCH + b) * HDIM + h;
    const float e = (float)E[idx];
    const float hv = (float)hse[idx];
    den += e;
    num += e * hv;
  }
  const size_t pi = ((size_t)tc * BATCH + b) * HDIM + h;
  pnum[pi] = num;
  pden[pi] = den;
}

__global__ __launch_bounds__(256) void k_final(
    const float* __restrict__ pnum, const float* __restrict__ pden,
    float* __restrict__ out) {
  const int i = blockIdx.x * 256 + threadIdx.x;   // b*512+h
  float n = 0.f, d = 0.f;
#pragma unroll
  for (int z = 0; z < 4; ++z) {
    n += pnum[(size_t)z * 32768 + i];
    d += pden[(size_t)z * 32768 + i];
  }
  out[i] = n / d;
}

// ---------------------------------------------------------------------------
extern "C" void kernel_launch(void* const* d_in, const int* in_sizes, int n_in,
                              void* d_out, int out_size, void* d_ws, size_t ws_size,
                              hipStream_t stream) {
  const float* x   = (const float*)d_in[0];
  const float* Wih = (const float*)d_in[1];
  const float* Whh = (const float*)d_in[2];
  const float* bih = (const float*)d_in[3];
  const float* bhh = (const float*)d_in[4];
  const float* Wat = (const float*)d_in[5];
  const float* bat = (const float*)d_in[6];
  float* out = (float*)d_out;

  char* ws = (char*)d_ws;
  const size_t REGA_BYTES = (size_t)64 * 1024 * 1024;                        // xT then E
  const size_t HS_BYTES = (size_t)(TLEN + 1) * BATCH * HDIM * sizeof(f16_t); // 67.2MB
  const size_t WAT_BYTES = (size_t)64 * HDIM * 8 * sizeof(f16_t);            // 512KB
  const size_t P_BYTES = (size_t)4 * BATCH * HDIM * sizeof(float);           // 512KB

  f16_t* xT = (f16_t*)ws;
  f16_t* E  = (f16_t*)ws;
  f16_t* hs = (f16_t*)(ws + REGA_BYTES);
  f16_t* WaT = (f16_t*)(ws + REGA_BYTES + HS_BYTES);
  float* pnum = (float*)(ws + REGA_BYTES + HS_BYTES + WAT_BYTES);
  float* pden = (float*)(ws + REGA_BYTES + HS_BYTES + WAT_BYTES + P_BYTES);

  const size_t SLAB = (size_t)BATCH * HDIM * sizeof(f16_t);   // 64KB
  // slab 0 = h(0) = zeros; slabs 1..1024 = 0xFEFE sentinel (re-poison every
  // launch: the sentinel IS the readiness protocol).
  hipMemsetAsync(hs, 0, SLAB, stream);
  hipMemsetAsync((char*)hs + SLAB, 0xFE, (size_t)TLEN * SLAB, stream);

  k_prep_x<<<dim3(TLEN), 256, 0, stream>>>(x, xT);
  k_prep_w<<<dim3(128), 256, 0, stream>>>(Wat, WaT);
  k_lstm<<<dim3(128), 512, 0, stream>>>(Whh, Wih, bih, bhh, xT, hs);

  const f16_t* hse = hs + (size_t)BATCH * HDIM;   // slab 1 == reference hs[0]
  k_attn<<<dim3(1024, 8), 256, 0, stream>>>(hse, WaT, bat, E);
  k_pool<<<dim3(64, 2, 4), 256, 0, stream>>>(E, hse, pnum, pden);
  k_final<<<dim3(128), 256, 0, stream>>>(pnum, pden, out);
}